// Round 13
// baseline (117.189 us; speedup 1.0000x reference)
//
#include <hip/hip_runtime.h>
#include <hip/hip_bf16.h>

#define T 50
#define NB 64
#define NS 512
#define START_TAG 48
#define STOP_TAG 49

typedef _Float16 f16_t;
typedef _Float16 f16x2 __attribute__((ext_vector_type(2)));
typedef _Float16 f16x4 __attribute__((ext_vector_type(4)));
typedef float    f32x4 __attribute__((ext_vector_type(4)));

static constexpr float LOG2E = 1.4426950408889634f;
static constexpr float LN2F  = 0.6931471805599453f;
static constexpr float S_E   = 6.0f;     // static log2 shift folded out of E
#define NEG_BIG (-1.0e38f)

__device__ __forceinline__ float fexp2(float x) { return __builtin_amdgcn_exp2f(x); }
__device__ __forceinline__ float flog2(float x) { return __builtin_amdgcn_logf(x); }
__device__ __forceinline__ f16x2 bcast_h2(f16x2 v, int src) {
    unsigned u = __builtin_amdgcn_readlane(__builtin_bit_cast(unsigned, v), src);
    return __builtin_bit_cast(f16x2, u);
}
__device__ __forceinline__ f16x2 pack_h2(float a, float b) {
    return __builtin_bit_cast(f16x2, __builtin_amdgcn_cvt_pkrtz(a, b));
}

// Full-wave (64-lane) fmax via DPP (VALU pipe) -> uniform value via lane 63.
__device__ __forceinline__ float wave_fmax_dpp(float x) {
#define DPP_STEP(ctrl)                                                        \
    do {                                                                      \
        int _s = __builtin_bit_cast(int, x);                                  \
        int _p = __builtin_amdgcn_update_dpp(_s, _s, (ctrl), 0xf, 0xf, false);\
        x = fmaxf(x, __builtin_bit_cast(float, _p));                          \
    } while (0)
    DPP_STEP(0x111);  // row_shr:1
    DPP_STEP(0x112);  // row_shr:2
    DPP_STEP(0x114);  // row_shr:4
    DPP_STEP(0x118);  // row_shr:8
    DPP_STEP(0x142);  // row_bcast:15
    DPP_STEP(0x143);  // row_bcast:31
#undef DPP_STEP
    return __builtin_bit_cast(float,
        __builtin_amdgcn_readlane(__builtin_bit_cast(int, x), 63));
}

// =====================================================================
// DUAL-CHAIN chunk kernel: block p owns chunks 2p (A) and 2p+1 (B);
// each wave runs BOTH column-slice recurrences interleaved in one
// instruction stream -> chain A's scale/cvt VALU overlaps chain B's
// MFMA chain (separate pipes, same wave). Occupancy path is closed
// (128-reg quantum, r11/r12), so ILP replaces the missing TLP.
// Register peak: Afrag 32 (SHARED by chains) + BtA/BtB 16 + accA/accB
// 32 + misc ~20 = ~100 < 128 -> same 4-wave class, no spill.
// Math per chain identical to r9..r12 (HW-verified): M = C^T,
// M' = D_s*(E^T*M); mfma_f32_16x16x16f16 D-layout == B-layout.
// =====================================================================
template<int NPAIR, int CHLT>   // chunks = 2*NPAIR, CHLT steps each
__global__ __launch_bounds__(256, 4)
void crf_chunk2(const float* __restrict__ feats, const int* __restrict__ mask,
                const float* __restrict__ trans, f16_t* __restrict__ wsCt,
                float* __restrict__ wsD) {
    const int p    = blockIdx.x;          // chunk pair
    const int b    = blockIdx.y;          // batch
    const int tid  = threadIdx.x;
    const int w    = tid >> 6;            // wave = column-slice owner
    const int lane = tid & 63;
    const int l15  = lane & 15;
    const int q    = lane >> 4;
    const int NCHT = 2 * NPAIR;

    __shared__ float sF[2 * CHLT][64];    // rows 0..CHLT-1 = chunk A, rest = B
    __shared__ f16_t Ml[64 * 72];         // epilogue transpose (16B-aligned rows)

    const int cA  = 2 * p;
    const int t0A = cA * CHLT + 1;        // t0B = t0A + CHLT

    // ---- A-const: E^T tiles. A(mb,kb) elem j = E[16kb+4q+j][16mb+l15]
    f16x4 Afrag[4][4];
    #pragma unroll
    for (int mb = 0; mb < 4; mb++)
        #pragma unroll
        for (int kb = 0; kb < 4; kb++) {
            f16x4 v;
            #pragma unroll
            for (int j = 0; j < 4; j++) {
                const int kk = 16 * kb + 4 * q + j;   // row of E
                const int mm = 16 * mb + l15;         // col of E
                float x = 0.f;
                if (kk < T && mm < T) x = fexp2(fmaf(trans[kk * T + mm], LOG2E, -S_E));
                v[j] = (f16_t)x;
            }
            Afrag[mb][kb] = v;
        }

    // ---- preload sF for BOTH chunks (rows are contiguous in time)
    for (int r = w; r < 2 * CHLT; r += 4) {
        int tl = t0A + r;
        bool val = (tl < NS) && (lane < T);
        tl = tl < NS ? tl : NS - 1;
        float fv = val ? feats[((size_t)b * NS + tl) * T + lane] : 0.f;
        sF[r][lane] = val ? fexp2(fv * LOG2E) : 0.f;
    }

    // ---- mask bitmaps: one ballot covers both chunks (32 steps)
    unsigned bmA, bmB;
    {
        int g = t0A + lane;
        int mv = (lane < 2 * CHLT && g < NS) ? mask[b * NS + g] : 0;
        unsigned long long bm = __ballot(mv != 0);
        bmA = (unsigned)(bm & ((1ull << CHLT) - 1));
        bmB = (unsigned)((bm >> CHLT) & ((1ull << CHLT) - 1));
    }
    __syncthreads();                      // sF visible to all waves

    // ---- init both slices of M = I: tile rb is I-block (rb, w)
    f16x4 BtA[4], BtB[4];
    #pragma unroll
    for (int rb = 0; rb < 4; rb++) {
        f16x4 v;
        #pragma unroll
        for (int j = 0; j < 4; j++)
            v[j] = (f16_t)((rb == w && 4 * q + j == l15) ? 1.f : 0.f);
        BtA[rb] = v; BtB[rb] = v;
    }

    float DA = 0.f, DB = 0.f;
    float m1A = 1.f, m2A = 1.f, m1B = 1.f, m2B = 1.f;

    const f32x4 zz = {0.f, 0.f, 0.f, 0.f};

    for (int s = 0; s < CHLT; s++) {
        const bool doA = (bmA >> s) & 1u;
        const bool doB = (bmB >> s) & 1u;

        // descales (SALU-ish, off critical path; exact pow2, D compensates)
        float dscA = 1.f, dscB = 1.f;
        if (doA) {
            int e = (int)((__float_as_uint(m2A) >> 23) & 255) - 127;
            e = e > 14 ? 14 : (e < -14 ? -14 : e);
            dscA = __uint_as_float((unsigned)(127 - e) << 23);
            DA += (float)e + S_E;
        }
        if (doB) {
            int e = (int)((__float_as_uint(m2B) >> 23) & 255) - 127;
            e = e > 14 ? 14 : (e < -14 ? -14 : e);
            dscB = __uint_as_float((unsigned)(127 - e) << 23);
            DB += (float)e + S_E;
        }

        // MFMAs: both chains issued together -> 8 independent depth-4 chains
        f32x4 accA[4], accB[4];
        if (doA) {
            #pragma unroll
            for (int mb = 0; mb < 4; mb++)
                accA[mb] = __builtin_amdgcn_mfma_f32_16x16x16f16(Afrag[mb][0], BtA[0], zz, 0, 0, 0);
        }
        if (doB) {
            #pragma unroll
            for (int mb = 0; mb < 4; mb++)
                accB[mb] = __builtin_amdgcn_mfma_f32_16x16x16f16(Afrag[mb][0], BtB[0], zz, 0, 0, 0);
        }
        #pragma unroll
        for (int kb = 1; kb < 4; kb++) {
            if (doA) {
                #pragma unroll
                for (int mb = 0; mb < 4; mb++)
                    accA[mb] = __builtin_amdgcn_mfma_f32_16x16x16f16(Afrag[mb][kb], BtA[kb], accA[mb], 0, 0, 0);
            }
            if (doB) {
                #pragma unroll
                for (int mb = 0; mb < 4; mb++)
                    accB[mb] = __builtin_amdgcn_mfma_f32_16x16x16f16(Afrag[mb][kb], BtB[kb], accB[mb], 0, 0, 0);
            }
        }

        // scale + RNE f16 back to Bt (chain A then B; scheduler overlaps
        // A's VALU with B's MFMA tail)
        if (doA) {
            float wm = 0.f;
            #pragma unroll
            for (int mb = 0; mb < 4; mb++) {
                f32x4 cs = *(const f32x4*)&sF[s][16 * mb + 4 * q];
                float v0 = accA[mb][0] * (cs[0] * dscA);
                float v1 = accA[mb][1] * (cs[1] * dscA);
                float v2 = accA[mb][2] * (cs[2] * dscA);
                float v3 = accA[mb][3] * (cs[3] * dscA);
                wm = fmaxf(wm, fmaxf(fmaxf(v0, v1), fmaxf(v2, v3)));
                f16x4 hv;
                hv[0] = (f16_t)v0; hv[1] = (f16_t)v1;
                hv[2] = (f16_t)v2; hv[3] = (f16_t)v3;
                BtA[mb] = hv;
            }
            m2A = m1A; m1A = wave_fmax_dpp(wm);
        }
        if (doB) {
            float wm = 0.f;
            #pragma unroll
            for (int mb = 0; mb < 4; mb++) {
                f32x4 cs = *(const f32x4*)&sF[CHLT + s][16 * mb + 4 * q];
                float v0 = accB[mb][0] * (cs[0] * dscB);
                float v1 = accB[mb][1] * (cs[1] * dscB);
                float v2 = accB[mb][2] * (cs[2] * dscB);
                float v3 = accB[mb][3] * (cs[3] * dscB);
                wm = fmaxf(wm, fmaxf(fmaxf(v0, v1), fmaxf(v2, v3)));
                f16x4 hv;
                hv[0] = (f16_t)v0; hv[1] = (f16_t)v1;
                hv[2] = (f16_t)v2; hv[3] = (f16_t)v3;
                BtB[mb] = hv;
            }
            m2B = m1B; m1B = wave_fmax_dpp(wm);
        }
    }

    // ---- epilogue: transpose/store chunk A, then chunk B (Ml reused)
    const int P2  = 72;
    const int row = tid >> 2;             // 0..63
    const int seg = tid & 3;              // 32 B segment
    {
        #pragma unroll
        for (int rb = 0; rb < 4; rb++) {
            f16x4 v = BtA[rb];
            #pragma unroll
            for (int r = 0; r < 4; r++)
                Ml[(16 * rb + 4 * q + r) * P2 + 16 * w + l15] = v[r];
        }
        __syncthreads();
        const f16_t* src = &Ml[row * P2 + seg * 16];
        f16_t* dst = wsCt + ((size_t)(b * NCHT + cA)) * 4096 + row * 64 + seg * 16;
        ((int4*)dst)[0] = *(const int4*)&src[0];
        ((int4*)dst)[1] = *(const int4*)&src[8];
        __syncthreads();                  // WAR: all reads done before B writes
    }
    {
        #pragma unroll
        for (int rb = 0; rb < 4; rb++) {
            f16x4 v = BtB[rb];
            #pragma unroll
            for (int r = 0; r < 4; r++)
                Ml[(16 * rb + 4 * q + r) * P2 + 16 * w + l15] = v[r];
        }
        __syncthreads();
        const f16_t* src = &Ml[row * P2 + seg * 16];
        f16_t* dst = wsCt + ((size_t)(b * NCHT + cA + 1)) * 4096 + row * 64 + seg * 16;
        ((int4*)dst)[0] = *(const int4*)&src[0];
        ((int4*)dst)[1] = *(const int4*)&src[8];
    }
    if (lane == 0) {
        wsD[(b * NCHT + cA) * 4 + w]     = DA;
        wsD[(b * NCHT + cA + 1) * 4 + w] = DB;
    }
}

// =====================================================================
// Single-chain chunk kernel (r12-verified, fallback tiers).
// =====================================================================
template<int NCHT, int CHLT>
__global__ __launch_bounds__(256, 4)
void crf_chunk(const float* __restrict__ feats, const int* __restrict__ mask,
               const float* __restrict__ trans, f16_t* __restrict__ wsCt,
               float* __restrict__ wsD) {
    const int c    = blockIdx.x;
    const int b    = blockIdx.y;
    const int tid  = threadIdx.x;
    const int w    = tid >> 6;
    const int lane = tid & 63;
    const int l15  = lane & 15;
    const int q    = lane >> 4;

    __shared__ float sF[CHLT][64];
    __shared__ f16_t Ml[64 * 72];

    const int t0  = c * CHLT + 1;
    const int nst = (NS - t0 < CHLT) ? (NS - t0) : CHLT;

    f16x4 Afrag[4][4];
    #pragma unroll
    for (int mb = 0; mb < 4; mb++)
        #pragma unroll
        for (int kb = 0; kb < 4; kb++) {
            f16x4 v;
            #pragma unroll
            for (int j = 0; j < 4; j++) {
                const int kk = 16 * kb + 4 * q + j;
                const int mm = 16 * mb + l15;
                float x = 0.f;
                if (kk < T && mm < T) x = fexp2(fmaf(trans[kk * T + mm], LOG2E, -S_E));
                v[j] = (f16_t)x;
            }
            Afrag[mb][kb] = v;
        }

    for (int r = w; r < CHLT; r += 4) {
        int tl = t0 + r; tl = tl < NS ? tl : NS - 1;
        float fv = (lane < T && r < nst) ? feats[((size_t)b * NS + tl) * T + lane] : 0.f;
        sF[r][lane] = (lane < T && r < nst) ? fexp2(fv * LOG2E) : 0.f;
    }

    unsigned long long bm;
    {
        int tl = t0 + lane; tl = tl < NS ? tl : NS - 1;
        int mv = (lane < nst) ? mask[b * NS + tl] : 0;
        bm = __ballot(mv != 0);
    }
    __syncthreads();

    f16x4 Bt[4];
    #pragma unroll
    for (int rb = 0; rb < 4; rb++) {
        f16x4 v;
        #pragma unroll
        for (int j = 0; j < 4; j++)
            v[j] = (f16_t)((rb == w && 4 * q + j == l15) ? 1.f : 0.f);
        Bt[rb] = v;
    }

    float D  = 0.f;
    float m1 = 1.f, m2 = 1.f;

    for (int s = 0; s < nst; s++) {
        if ((bm >> s) & 1ull) {
            int ebits = (int)((__float_as_uint(m2) >> 23) & 255) - 127;
            ebits = ebits > 14 ? 14 : (ebits < -14 ? -14 : ebits);
            const float descale = __uint_as_float((unsigned)(127 - ebits) << 23);
            D += (float)ebits + S_E;

            const f32x4 zz = {0.f, 0.f, 0.f, 0.f};
            f32x4 acc[4];
            #pragma unroll
            for (int mb = 0; mb < 4; mb++)
                acc[mb] = __builtin_amdgcn_mfma_f32_16x16x16f16(Afrag[mb][0], Bt[0], zz, 0, 0, 0);
            #pragma unroll
            for (int kb = 1; kb < 4; kb++)
                #pragma unroll
                for (int mb = 0; mb < 4; mb++)
                    acc[mb] = __builtin_amdgcn_mfma_f32_16x16x16f16(Afrag[mb][kb], Bt[kb], acc[mb], 0, 0, 0);

            float wm = 0.f;
            #pragma unroll
            for (int mb = 0; mb < 4; mb++) {
                f32x4 cs = *(const f32x4*)&sF[s][16 * mb + 4 * q];
                float v0 = acc[mb][0] * (cs[0] * descale);
                float v1 = acc[mb][1] * (cs[1] * descale);
                float v2 = acc[mb][2] * (cs[2] * descale);
                float v3 = acc[mb][3] * (cs[3] * descale);
                wm = fmaxf(wm, fmaxf(fmaxf(v0, v1), fmaxf(v2, v3)));
                f16x4 hv;
                hv[0] = (f16_t)v0; hv[1] = (f16_t)v1;
                hv[2] = (f16_t)v2; hv[3] = (f16_t)v3;
                Bt[mb] = hv;
            }

            m2 = m1;
            m1 = wave_fmax_dpp(wm);
        }
    }

    {
        const int P2 = 72;
        #pragma unroll
        for (int rb = 0; rb < 4; rb++) {
            f16x4 v = Bt[rb];
            #pragma unroll
            for (int r = 0; r < 4; r++)
                Ml[(16 * rb + 4 * q + r) * P2 + 16 * w + l15] = v[r];
        }
        __syncthreads();
        const int row = tid >> 2;
        const int seg = tid & 3;
        const f16_t* src = &Ml[row * P2 + seg * 16];
        f16_t* dst = wsCt + ((size_t)(b * NCHT + c)) * 4096 + row * 64 + seg * 16;
        ((int4*)dst)[0] = *(const int4*)&src[0];
        ((int4*)dst)[1] = *(const int4*)&src[8];
    }
    if (lane == 0) wsD[(b * NCHT + c) * 4 + w] = D;
}

// =====================================================================
// Kernel 2: 2 waves per batch. Wave 0: part-chain over NCHT chunk
// matrices (lane j holds column j of C, 128 B contiguous, double-
// buffered bufA/bufB). Wave 1: gold score. Dq[lane>>4] absorbs the
// per-wave renorm.
// =====================================================================
template<int NCHT>
__global__ __launch_bounds__(128, 1)
void crf_combine(const float* __restrict__ feats, const int* __restrict__ mask,
                 const int* __restrict__ tags, const float* __restrict__ trans,
                 const f16_t* __restrict__ wsCt, const float* __restrict__ wsD,
                 float* __restrict__ out) {
    const int b    = blockIdx.x;
    const int tid  = threadIdx.x;
    const int wv   = tid >> 6;
    const int lane = tid & 63;

    __shared__ float sGold;
    float fwd = 0.f;

    if (wv == 1) {
        float gsum = 0.f;
        int   lcnt = 0;
        for (int s = lane; s < NS; s += 64) {
            int   m  = mask[b * NS + s];
            int   tg = tags[b * NS + s];
            int   pv = (s == 0) ? START_TAG : tags[b * NS + s - 1];
            float e  = feats[((size_t)b * NS + s) * T + tg];
            float tr = trans[pv * T + tg];
            if (m) { gsum += e + tr; lcnt += 1; }
        }
        #pragma unroll
        for (int off = 32; off > 0; off >>= 1) {
            gsum += __shfl_down(gsum, off, 64);
            lcnt += __shfl_down(lcnt, off, 64);
        }
        if (lane == 0) sGold = gsum + trans[tags[b * NS + lcnt - 1] * T + STOP_TAG];
    } else {
        float part = (lane < T)
            ? (feats[(size_t)b * NS * T + lane] + trans[START_TAG * T + lane]) * LOG2E
            : NEG_BIG;

        float Dq[NCHT];
        #pragma unroll
        for (int cc = 0; cc < NCHT; cc++)
            Dq[cc] = wsD[(b * NCHT + cc) * 4 + (lane >> 4)];

        int bufA[32], bufB[32];
        {
            const f16_t* src = wsCt + (size_t)b * NCHT * 4096 + lane * 64;
            #pragma unroll
            for (int kk = 0; kk < 8; kk++)
                *(int4*)&bufA[4 * kk] = ((const int4*)src)[kk];
        }

        auto cbody = [&](int (&cur)[32], int (&nxt)[32], int cc) {
            if (cc + 1 < NCHT) {
                const f16_t* src = wsCt + (size_t)(b * NCHT + cc + 1) * 4096 + lane * 64;
                #pragma unroll
                for (int kk = 0; kk < 8; kk++)
                    *(int4*)&nxt[4 * kk] = ((const int4*)src)[kk];
            }

            float tmp = part + Dq[cc];
            float sft = wave_fmax_dpp(tmp);
            float ex  = fexp2(tmp - sft);
            float exo = __shfl_xor(ex, 1, 64);
            f16x2 pk  = pack_h2(ex, exo);

            float a0 = 0.f, a1 = 0.f, a2 = 0.f, a3 = 0.f;
            #pragma unroll
            for (int k = 0; k < 25; k += 4) {
                a0 = __builtin_amdgcn_fdot2(bcast_h2(pk, 2 * k), __builtin_bit_cast(f16x2, cur[k]), a0, false);
                if (k + 1 < 25) a1 = __builtin_amdgcn_fdot2(bcast_h2(pk, 2 * (k + 1)), __builtin_bit_cast(f16x2, cur[k + 1]), a1, false);
                if (k + 2 < 25) a2 = __builtin_amdgcn_fdot2(bcast_h2(pk, 2 * (k + 2)), __builtin_bit_cast(f16x2, cur[k + 2]), a2, false);
                if (k + 3 < 25) a3 = __builtin_amdgcn_fdot2(bcast_h2(pk, 2 * (k + 3)), __builtin_bit_cast(f16x2, cur[k + 3]), a3, false);
            }
            part = sft + flog2((a0 + a1) + (a2 + a3));
        };

        #pragma unroll
        for (int pp = 0; pp < NCHT / 2; pp++) {
            cbody(bufA, bufB, 2 * pp);
            cbody(bufB, bufA, 2 * pp + 1);
        }

        float v = (lane < T) ? part + trans[lane * T + STOP_TAG] * LOG2E : NEG_BIG;
        float mx = wave_fmax_dpp(v);
        float ee = (lane < T) ? fexp2(v - mx) : 0.f;
        #pragma unroll
        for (int off = 32; off > 0; off >>= 1) ee += __shfl_xor(ee, off, 64);
        fwd = (mx + flog2(ee)) * LN2F;
    }

    __syncthreads();
    if (tid == 0) atomicAdd(out, fwd - sGold);
}

extern "C" void kernel_launch(void* const* d_in, const int* in_sizes, int n_in,
                              void* d_out, int out_size, void* d_ws, size_t ws_size,
                              hipStream_t stream) {
    const float* feats = (const float*)d_in[0];
    const int*   mask  = (const int*)d_in[1];
    const int*   tags  = (const int*)d_in[2];
    const float* trans = (const float*)d_in[3];
    float* out = (float*)d_out;

    (void)hipMemsetAsync(out, 0, sizeof(float) * out_size, stream);

    const size_t matBytes32 = (size_t)NB * 32 * 4096 * sizeof(f16_t);
    const size_t need32     = matBytes32 + (size_t)NB * 32 * 4 * sizeof(float);
    const size_t matBytes16 = (size_t)NB * 16 * 4096 * sizeof(f16_t);
    const size_t need16     = matBytes16 + (size_t)NB * 16 * 4 * sizeof(float);

    if (ws_size >= need32) {
        // preferred: 32 chunks x 16 steps, dual-chain waves (8 chains/SIMD)
        f16_t* wsCt = (f16_t*)d_ws;
        float* wsD  = (float*)((char*)d_ws + matBytes32);
        crf_chunk2<16, 16><<<dim3(16, NB), 256, 0, stream>>>(feats, mask, trans, wsCt, wsD);
        crf_combine<32><<<NB, 128, 0, stream>>>(feats, mask, tags, trans, wsCt, wsD, out);
    } else if (ws_size >= need16) {
        // r12-verified: 16 chunks x 32 steps, single-chain
        f16_t* wsCt = (f16_t*)d_ws;
        float* wsD  = (float*)((char*)d_ws + matBytes16);
        crf_chunk<16, 32><<<dim3(16, NB), 256, 0, stream>>>(feats, mask, trans, wsCt, wsD);
        crf_combine<16><<<NB, 128, 0, stream>>>(feats, mask, tags, trans, wsCt, wsD, out);
    } else {
        // minimal: 8 chunks x 64 steps (fits 4.2 MB)
        const size_t matBytes8 = (size_t)NB * 8 * 4096 * sizeof(f16_t);
        f16_t* wsCt = (f16_t*)d_ws;
        float* wsD  = (float*)((char*)d_ws + matBytes8);
        crf_chunk<8, 64><<<dim3(8, NB), 256, 0, stream>>>(feats, mask, trans, wsCt, wsD);
        crf_combine<8><<<NB, 128, 0, stream>>>(feats, mask, tags, trans, wsCt, wsD, out);
    }
}

// Round 14
// 106.527 us; speedup vs baseline: 1.1001x; 1.1001x over previous
//
#include <hip/hip_runtime.h>
#include <hip/hip_bf16.h>

#define T 50
#define NB 64
#define NS 512
#define START_TAG 48
#define STOP_TAG 49

typedef _Float16 f16_t;
typedef _Float16 f16x2 __attribute__((ext_vector_type(2)));
typedef _Float16 f16x4 __attribute__((ext_vector_type(4)));
typedef float    f32x4 __attribute__((ext_vector_type(4)));

static constexpr float LOG2E = 1.4426950408889634f;
static constexpr float LN2F  = 0.6931471805599453f;
static constexpr float S_E   = 6.0f;     // static log2 shift folded out of E
#define NEG_BIG (-1.0e38f)

__device__ __forceinline__ float fexp2(float x) { return __builtin_amdgcn_exp2f(x); }
__device__ __forceinline__ float flog2(float x) { return __builtin_amdgcn_logf(x); }
__device__ __forceinline__ f16x2 bcast_h2(f16x2 v, int src) {
    unsigned u = __builtin_amdgcn_readlane(__builtin_bit_cast(unsigned, v), src);
    return __builtin_bit_cast(f16x2, u);
}
__device__ __forceinline__ f16x2 pack_h2(float a, float b) {
    return __builtin_bit_cast(f16x2, __builtin_amdgcn_cvt_pkrtz(a, b));
}

// Full-wave (64-lane) fmax via DPP (VALU pipe) -> uniform value via lane 63.
__device__ __forceinline__ float wave_fmax_dpp(float x) {
#define DPP_STEP(ctrl)                                                        \
    do {                                                                      \
        int _s = __builtin_bit_cast(int, x);                                  \
        int _p = __builtin_amdgcn_update_dpp(_s, _s, (ctrl), 0xf, 0xf, false);\
        x = fmaxf(x, __builtin_bit_cast(float, _p));                          \
    } while (0)
    DPP_STEP(0x111);  // row_shr:1
    DPP_STEP(0x112);  // row_shr:2
    DPP_STEP(0x114);  // row_shr:4
    DPP_STEP(0x118);  // row_shr:8
    DPP_STEP(0x142);  // row_bcast:15
    DPP_STEP(0x143);  // row_bcast:31
#undef DPP_STEP
    return __builtin_bit_cast(float,
        __builtin_amdgcn_readlane(__builtin_bit_cast(int, x), 63));
}

// =====================================================================
// Kernel 1 (register-resident, column-sliced; r12-verified structure):
// 4 waves per (batch,chunk). M = C^T; wave w owns M columns [16w,16w+16)
// in regs (Bt[rb], 8 VGPRs). Step: acc[mb] = sum_kb A(mb,kb) x Bt[kb]
// (16 MFMAs, 4 indep depth-4 chains), row-scale by cs*descale (f32,
// exact pow2), RNE f16 back to Bt. mfma_f32_16x16x16f16 D-layout ==
// B-layout (HW-verified r8..r13).
// vs r12:
//  - wm via packed v_pk_max_f16 on the stored f16 words (post-rounding
//    max: its pow2 exponent is equally valid - D compensates exactly).
//    ~5 fewer VALU/step.
//  - block (0,0) zeroes `out` in the epilogue -> the hipMemsetAsync
//    GRAPH NODE is removed (same-stream dispatch order makes the zero
//    visible to the later combine dispatch). Tests the ~13us/node
//    residual theory (r0..r12: 3-node residual 62us; r7: 2-node 49us).
// =====================================================================
template<int NCHT, int CHLT>
__global__ __launch_bounds__(256, 6)
void crf_chunk(const float* __restrict__ feats, const int* __restrict__ mask,
               const float* __restrict__ trans, f16_t* __restrict__ wsCt,
               float* __restrict__ wsD, float* __restrict__ out, int out_size) {
    const int c    = blockIdx.x;          // chunk
    const int b    = blockIdx.y;          // batch
    const int tid  = threadIdx.x;
    const int w    = tid >> 6;            // wave = column-slice owner
    const int lane = tid & 63;
    const int l15  = lane & 15;
    const int q    = lane >> 4;

    __shared__ float sF[CHLT][64];        // 2^(f_t*log2e) per step / M-row
    __shared__ f16_t Ml[64 * 72];         // epilogue transpose (16B-aligned rows)

    const int t0  = c * CHLT + 1;
    const int nst = (NS - t0 < CHLT) ? (NS - t0) : CHLT;

    // ---- A-const: E^T tiles. A(mb,kb) elem j = E[16kb+4q+j][16mb+l15]
    f16x4 Afrag[4][4];
    #pragma unroll
    for (int mb = 0; mb < 4; mb++)
        #pragma unroll
        for (int kb = 0; kb < 4; kb++) {
            f16x4 v;
            #pragma unroll
            for (int j = 0; j < 4; j++) {
                const int kk = 16 * kb + 4 * q + j;   // row of E
                const int mm = 16 * mb + l15;         // col of E
                float x = 0.f;
                if (kk < T && mm < T) x = fexp2(fmaf(trans[kk * T + mm], LOG2E, -S_E));
                v[j] = (f16_t)x;
            }
            Afrag[mb][kb] = v;
        }

    // ---- preload sF (exp2 once); 4 waves stripe the rows
    for (int r = w; r < CHLT; r += 4) {
        int tl = t0 + r; tl = tl < NS ? tl : NS - 1;
        float fv = (lane < T && r < nst) ? feats[((size_t)b * NS + tl) * T + lane] : 0.f;
        sF[r][lane] = (lane < T && r < nst) ? fexp2(fv * LOG2E) : 0.f;
    }

    // ---- mask bitmap (one ballot; per-step test is SALU)
    unsigned long long bm;
    {
        int tl = t0 + lane; tl = tl < NS ? tl : NS - 1;
        int mv = (lane < nst) ? mask[b * NS + tl] : 0;
        bm = __ballot(mv != 0);
    }
    __syncthreads();                      // sF visible to all waves

    // ---- init wave's slice of M = I: tile rb is I-block (rb, w)
    f16x4 Bt[4];
    #pragma unroll
    for (int rb = 0; rb < 4; rb++) {
        f16x4 v;
        #pragma unroll
        for (int j = 0; j < 4; j++)
            v[j] = (f16_t)((rb == w && 4 * q + j == l15) ? 1.f : 0.f);
        Bt[rb] = v;
    }

    float D  = 0.f;
    float m1 = 1.f, m2 = 1.f;             // wave max from s-1, s-2 (delayed renorm)

    for (int s = 0; s < nst; s++) {
        if ((bm >> s) & 1ull) {
            // descale from max TWO doit-steps back (exact pow2; D compensates)
            int ebits = (int)((__float_as_uint(m2) >> 23) & 255) - 127;
            ebits = ebits > 14 ? 14 : (ebits < -14 ? -14 : ebits);
            const float descale = __uint_as_float((unsigned)(127 - ebits) << 23);
            D += (float)ebits + S_E;

            // 16 MFMAs: 4 independent depth-4 accumulate chains
            const f32x4 zz = {0.f, 0.f, 0.f, 0.f};
            f32x4 acc[4];
            #pragma unroll
            for (int mb = 0; mb < 4; mb++)
                acc[mb] = __builtin_amdgcn_mfma_f32_16x16x16f16(Afrag[mb][0], Bt[0], zz, 0, 0, 0);
            #pragma unroll
            for (int kb = 1; kb < 4; kb++)
                #pragma unroll
                for (int mb = 0; mb < 4; mb++)
                    acc[mb] = __builtin_amdgcn_mfma_f32_16x16x16f16(Afrag[mb][kb], Bt[kb], acc[mb], 0, 0, 0);

            // per-mb: load cs, fold descale (exact pow2), scale, RNE f16;
            // wm via packed f16 max on the stored words (v_pk_max_f16)
            f16x2 wmax2 = {(f16_t)0.f, (f16_t)0.f};
            #pragma unroll
            for (int mb = 0; mb < 4; mb++) {
                f32x4 cs = *(const f32x4*)&sF[s][16 * mb + 4 * q];
                float v0 = acc[mb][0] * (cs[0] * descale);
                float v1 = acc[mb][1] * (cs[1] * descale);
                float v2 = acc[mb][2] * (cs[2] * descale);
                float v3 = acc[mb][3] * (cs[3] * descale);
                f16x4 hv;
                hv[0] = (f16_t)v0; hv[1] = (f16_t)v1;   // RNE, matches prior rounds
                hv[2] = (f16_t)v2; hv[3] = (f16_t)v3;
                Bt[mb] = hv;       // D-layout == B-layout: feeds next step directly
                f16x2 lo = __builtin_shufflevector(hv, hv, 0, 1);
                f16x2 hi = __builtin_shufflevector(hv, hv, 2, 3);
                wmax2 = __builtin_elementwise_max(wmax2,
                          __builtin_elementwise_max(lo, hi));
            }
            float wm = fmaxf((float)wmax2[0], (float)wmax2[1]);

            m2 = m1;
            m1 = wave_fmax_dpp(wm);        // consumed two steps later
        }
    }

    // ---- epilogue: waves dump tiles -> barrier -> coalesced store
    {
        const int P2 = 72;
        #pragma unroll
        for (int rb = 0; rb < 4; rb++) {
            f16x4 v = Bt[rb];
            #pragma unroll
            for (int r = 0; r < 4; r++)
                Ml[(16 * rb + 4 * q + r) * P2 + 16 * w + l15] = v[r];
        }
        __syncthreads();
        // wsCt row j = M row j = column j of C (combine lane j's layout)
        const int row = tid >> 2;          // 0..63
        const int seg = tid & 3;           // 32 B segment
        const f16_t* src = &Ml[row * P2 + seg * 16];
        f16_t* dst = wsCt + ((size_t)(b * NCHT + c)) * 4096 + row * 64 + seg * 16;
        ((int4*)dst)[0] = *(const int4*)&src[0];
        ((int4*)dst)[1] = *(const int4*)&src[8];
    }
    if (lane == 0) wsD[(b * NCHT + c) * 4 + w] = D;   // per-wave (per-16-C-rows) shift

    // ---- zero `out` (replaces the hipMemsetAsync graph node; visible to
    //      the later combine dispatch via same-stream ordering)
    if (c == 0 && b == 0 && tid < out_size) out[tid] = 0.f;
}

// =====================================================================
// Kernel 2 (r12-verified, unchanged): 2 waves per batch. Wave 0: part-
// chain over NCHT chunk matrices (lane j holds column j of C, 128 B
// contiguous, double-buffered bufA/bufB). Wave 1: gold score.
// Dq[lane>>4] absorbs the per-wave renorm.
// =====================================================================
template<int NCHT>
__global__ __launch_bounds__(128, 1)
void crf_combine(const float* __restrict__ feats, const int* __restrict__ mask,
                 const int* __restrict__ tags, const float* __restrict__ trans,
                 const f16_t* __restrict__ wsCt, const float* __restrict__ wsD,
                 float* __restrict__ out) {
    const int b    = blockIdx.x;
    const int tid  = threadIdx.x;
    const int wv   = tid >> 6;
    const int lane = tid & 63;

    __shared__ float sGold;
    float fwd = 0.f;

    if (wv == 1) {
        float gsum = 0.f;
        int   lcnt = 0;
        for (int s = lane; s < NS; s += 64) {
            int   m  = mask[b * NS + s];
            int   tg = tags[b * NS + s];
            int   pv = (s == 0) ? START_TAG : tags[b * NS + s - 1];
            float e  = feats[((size_t)b * NS + s) * T + tg];
            float tr = trans[pv * T + tg];
            if (m) { gsum += e + tr; lcnt += 1; }
        }
        #pragma unroll
        for (int off = 32; off > 0; off >>= 1) {
            gsum += __shfl_down(gsum, off, 64);
            lcnt += __shfl_down(lcnt, off, 64);
        }
        if (lane == 0) sGold = gsum + trans[tags[b * NS + lcnt - 1] * T + STOP_TAG];
    } else {
        float part = (lane < T)
            ? (feats[(size_t)b * NS * T + lane] + trans[START_TAG * T + lane]) * LOG2E
            : NEG_BIG;

        float Dq[NCHT];
        #pragma unroll
        for (int cc = 0; cc < NCHT; cc++)
            Dq[cc] = wsD[(b * NCHT + cc) * 4 + (lane >> 4)];

        int bufA[32], bufB[32];
        {
            const f16_t* src = wsCt + (size_t)b * NCHT * 4096 + lane * 64;
            #pragma unroll
            for (int kk = 0; kk < 8; kk++)
                *(int4*)&bufA[4 * kk] = ((const int4*)src)[kk];
        }

        auto cbody = [&](int (&cur)[32], int (&nxt)[32], int cc) {
            if (cc + 1 < NCHT) {
                const f16_t* src = wsCt + (size_t)(b * NCHT + cc + 1) * 4096 + lane * 64;
                #pragma unroll
                for (int kk = 0; kk < 8; kk++)
                    *(int4*)&nxt[4 * kk] = ((const int4*)src)[kk];
            }

            float tmp = part + Dq[cc];
            float sft = wave_fmax_dpp(tmp);
            float ex  = fexp2(tmp - sft);
            float exo = __shfl_xor(ex, 1, 64);
            f16x2 pk  = pack_h2(ex, exo);

            float a0 = 0.f, a1 = 0.f, a2 = 0.f, a3 = 0.f;
            #pragma unroll
            for (int k = 0; k < 25; k += 4) {
                a0 = __builtin_amdgcn_fdot2(bcast_h2(pk, 2 * k), __builtin_bit_cast(f16x2, cur[k]), a0, false);
                if (k + 1 < 25) a1 = __builtin_amdgcn_fdot2(bcast_h2(pk, 2 * (k + 1)), __builtin_bit_cast(f16x2, cur[k + 1]), a1, false);
                if (k + 2 < 25) a2 = __builtin_amdgcn_fdot2(bcast_h2(pk, 2 * (k + 2)), __builtin_bit_cast(f16x2, cur[k + 2]), a2, false);
                if (k + 3 < 25) a3 = __builtin_amdgcn_fdot2(bcast_h2(pk, 2 * (k + 3)), __builtin_bit_cast(f16x2, cur[k + 3]), a3, false);
            }
            part = sft + flog2((a0 + a1) + (a2 + a3));
        };

        #pragma unroll
        for (int pp = 0; pp < NCHT / 2; pp++) {
            cbody(bufA, bufB, 2 * pp);
            cbody(bufB, bufA, 2 * pp + 1);
        }

        float v = (lane < T) ? part + trans[lane * T + STOP_TAG] * LOG2E : NEG_BIG;
        float mx = wave_fmax_dpp(v);
        float ee = (lane < T) ? fexp2(v - mx) : 0.f;
        #pragma unroll
        for (int off = 32; off > 0; off >>= 1) ee += __shfl_xor(ee, off, 64);
        fwd = (mx + flog2(ee)) * LN2F;
    }

    __syncthreads();
    if (tid == 0) atomicAdd(out, fwd - sGold);
}

extern "C" void kernel_launch(void* const* d_in, const int* in_sizes, int n_in,
                              void* d_out, int out_size, void* d_ws, size_t ws_size,
                              hipStream_t stream) {
    const float* feats = (const float*)d_in[0];
    const int*   mask  = (const int*)d_in[1];
    const int*   tags  = (const int*)d_in[2];
    const float* trans = (const float*)d_in[3];
    float* out = (float*)d_out;

    // NO hipMemsetAsync: `out` is zeroed inside crf_chunk (block (0,0));
    // same-stream ordering guarantees visibility to crf_combine.

    const size_t matBytes16 = (size_t)NB * 16 * 4096 * sizeof(f16_t);
    const size_t need16     = matBytes16 + (size_t)NB * 16 * 4 * sizeof(float);

    if (ws_size >= need16) {
        // preferred: 16 chunks x 32 steps, 1024 blocks x 4 waves
        f16_t* wsCt = (f16_t*)d_ws;
        float* wsD  = (float*)((char*)d_ws + matBytes16);
        crf_chunk<16, 32><<<dim3(16, NB), 256, 0, stream>>>(feats, mask, trans, wsCt, wsD, out, out_size);
        crf_combine<16><<<NB, 128, 0, stream>>>(feats, mask, tags, trans, wsCt, wsD, out);
    } else {
        // fallback: 8 chunks x 64 steps (fits 4.2 MB)
        const size_t matBytes8 = (size_t)NB * 8 * 4096 * sizeof(f16_t);
        f16_t* wsCt = (f16_t*)d_ws;
        float* wsD  = (float*)((char*)d_ws + matBytes8);
        crf_chunk<8, 64><<<dim3(8, NB), 256, 0, stream>>>(feats, mask, trans, wsCt, wsD, out, out_size);
        crf_combine<8><<<NB, 128, 0, stream>>>(feats, mask, tags, trans, wsCt, wsD, out);
    }
}